// Round 6
// baseline (458.219 us; speedup 1.0000x reference)
//
#include <hip/hip_runtime.h>

#define NEG_SLOPE 0.01f
typedef unsigned short ushort_t;

#define CHUNK 32768       // edges per histogram/reorder block
#define BSHIFT 9          // 512 nodes per dst-bucket

static __device__ __forceinline__ float bf2f(ushort_t u) {
    return __uint_as_float(((unsigned int)u) << 16);
}
static __device__ __forceinline__ ushort_t f2bf(float f) {
    unsigned int x = __float_as_uint(f);
    x += 0x7fffu + ((x >> 16) & 1u);   // round-to-nearest-even
    return (ushort_t)(x >> 16);
}
static __device__ __forceinline__ float bcastf(float v, int lane) {
    return __int_as_float(__builtin_amdgcn_readlane(__float_as_int(v), lane));
}

// ---------------------------------------------------------------------------
// phase A: per-chunk dst-bucket histogram (LDS) + global degree count
// grid = nch blocks x 1024
// ---------------------------------------------------------------------------
__global__ __launch_bounds__(1024) void hist_kernel(const int* __restrict__ dst,
                                                    int* __restrict__ cnt,
                                                    int* __restrict__ m,
                                                    int e, int nb_buckets, int nch) {
    __shared__ int lcnt[256];
    int t = threadIdx.x;
    if (t < nb_buckets) lcnt[t] = 0;
    __syncthreads();
    int base = blockIdx.x * CHUNK;
    for (int j = t; j < CHUNK; j += 1024) {
        int i = base + j;
        if (i < e) {
            int d = dst[i];
            atomicAdd(&cnt[d], 1);                 // degree (global)
            atomicAdd(&lcnt[d >> BSHIFT], 1);      // bucket hist (LDS)
        }
    }
    __syncthreads();
    if (t < nb_buckets) m[t * nch + blockIdx.x] = lcnt[t];   // bucket-major
}

// ---------------------------------------------------------------------------
// exclusive scan of m[0..M) in place (single block, 8 elems/thread, M<=8192)
// ---------------------------------------------------------------------------
__global__ __launch_bounds__(1024) void scanm_kernel(int* __restrict__ m, int M) {
    __shared__ int ts[1024];
    int t = threadIdx.x;
    int v[8], p[8];
    int s = 0;
    #pragma unroll
    for (int j = 0; j < 8; ++j) {
        int idx = t * 8 + j;
        v[j] = (idx < M) ? m[idx] : 0;
        s += v[j];
        p[j] = s;                       // inclusive within thread
    }
    ts[t] = s;
    __syncthreads();
    for (int st = 1; st < 1024; st <<= 1) {
        int x = (t >= st) ? ts[t - st] : 0;
        __syncthreads();
        ts[t] += x;
        __syncthreads();
    }
    int texcl = (t == 0) ? 0 : ts[t - 1];
    #pragma unroll
    for (int j = 0; j < 8; ++j) {
        int idx = t * 8 + j;
        if (idx < M) m[idx] = texcl + p[j] - v[j];   // exclusive
    }
}

// ---------------------------------------------------------------------------
// phase B: reorder edges into bucket-grouped ebuf (contiguous per chunk+bucket)
// grid = nch blocks x 1024
// ---------------------------------------------------------------------------
__global__ __launch_bounds__(1024) void reorder_kernel(const int* __restrict__ src,
                                                       const int* __restrict__ dst,
                                                       const int* __restrict__ m,
                                                       int2* __restrict__ ebuf,
                                                       int e, int nb_buckets, int nch) {
    __shared__ int cur[256];
    int t = threadIdx.x;
    if (t < nb_buckets) cur[t] = m[t * nch + blockIdx.x];
    __syncthreads();
    int base = blockIdx.x * CHUNK;
    for (int j = t; j < CHUNK; j += 1024) {
        int i = base + j;
        if (i < e) {
            int d = dst[i];
            int pos = atomicAdd(&cur[d >> BSHIFT], 1);
            ebuf[pos] = make_int2(src[i], d);
        }
    }
}

// ---------------------------------------------------------------------------
// phase C: local fill — one block per bucket; cursor atomics and csr stores
// stay within one XCD's L2 (full-line write-back)
// ---------------------------------------------------------------------------
__global__ __launch_bounds__(1024) void localfill_kernel(const int2* __restrict__ ebuf,
                                                         const int* __restrict__ m,
                                                         int* __restrict__ cursor,
                                                         int* __restrict__ csr,
                                                         int e, int nb_buckets, int nch) {
    int b  = blockIdx.x;
    int bs = m[b * nch];
    int be = (b + 1 < nb_buckets) ? m[(b + 1) * nch] : e;
    for (int i = bs + threadIdx.x; i < be; i += 1024) {
        int2 ed = ebuf[i];
        int slot = atomicAdd(&cursor[ed.y], 1);
        csr[slot] = ed.x;
    }
}

// ---------------------------------------------------------------------------
// per-256-block sums of PADDED degree counts
// ---------------------------------------------------------------------------
__global__ void blocksum_kernel(const int* __restrict__ cnt,
                                int* __restrict__ bsum, int n) {
    __shared__ int l[256];
    int i = blockIdx.x * 256 + threadIdx.x;
    l[threadIdx.x] = (i < n) ? ((cnt[i] + 7) & ~7) : 0;
    __syncthreads();
    for (int s = 128; s > 0; s >>= 1) {
        if (threadIdx.x < s) l[threadIdx.x] += l[threadIdx.x + s];
        __syncthreads();
    }
    if (threadIdx.x == 0) bsum[blockIdx.x] = l[0];
}

__global__ __launch_bounds__(1024) void scanb_kernel(int* __restrict__ bsum, int nb) {
    __shared__ int l[1024];
    int t = threadIdx.x;
    l[t] = (t < nb) ? bsum[t] : 0;
    __syncthreads();
    for (int s = 1; s < 1024; s <<= 1) {
        int v = (t >= s) ? l[t - s] : 0;
        __syncthreads();
        l[t] += v;
        __syncthreads();
    }
    int ex = (t == 0) ? 0 : l[t - 1];
    if (t < nb) bsum[t] = ex;
}

// rowptr (padded) + cursor + dinv + csr sentinel-init + zero sentinel xws rows
__global__ void rowptr_kernel(const int* __restrict__ cnt,
                              const int* __restrict__ bsum,
                              int* __restrict__ rowptr,
                              int* __restrict__ cursor,
                              float* __restrict__ dinv,
                              int* __restrict__ csr, int csr_len,
                              ushort_t* __restrict__ xwsA,
                              ushort_t* __restrict__ xwsB, int n) {
    __shared__ int l[256];
    int t = threadIdx.x;
    int i = blockIdx.x * 256 + t;
    int cvr = (i < n) ? cnt[i] : 0;        // real degree
    int cv  = (cvr + 7) & ~7;              // padded
    l[t] = cv;
    __syncthreads();
    for (int s = 1; s < 256; s <<= 1) {
        int v = (t >= s) ? l[t - s] : 0;
        __syncthreads();
        l[t] += v;
        __syncthreads();
    }
    int incl = l[t];
    int base = bsum[blockIdx.x];
    if (i < n) {
        int rp = base + incl - cv;
        rowptr[i] = rp;
        cursor[i] = rp;
        dinv[i]   = rsqrtf((float)cvr + 1.0f);
        if (i == n - 1) rowptr[n] = base + incl;
    }
    // sentinel-init padded CSR slots (grid-stride over whole csr)
    int gsz = gridDim.x * 256;
    for (int j = blockIdx.x * 256 + t; j < csr_len; j += gsz) csr[j] = n;
    if (blockIdx.x == 0 && t < 64) {       // zero sentinel row n
        xwsA[(size_t)n * 64 + t] = 0;
        xwsB[(size_t)n * 64 + t] = 0;
    }
}

// ---------------------------------------------------------------------------
// xws = (Xc @ W) * dinv[row]  (f32 in, bf16 out). W column in lane VGPRs,
// X rows broadcast via readlane. One wave = 16 rows.
// ---------------------------------------------------------------------------
__global__ __launch_bounds__(256) void gemm_rl(const float* __restrict__ Xc,
                                               const float* __restrict__ W,
                                               const float* __restrict__ dinv,
                                               ushort_t* __restrict__ xws, int n) {
    int lane = threadIdx.x & 63;
    int wv   = threadIdx.x >> 6;

    float Wreg[64];
    #pragma unroll
    for (int k = 0; k < 64; ++k) Wreg[k] = W[k * 64 + lane];

    int row0 = blockIdx.x * 64 + wv * 16;
    int lr = lane >> 4;
    int lc = lane & 15;

    #pragma unroll 1
    for (int it = 0; it < 4; ++it) {
        int r = row0 + it * 4;
        float4 xv = make_float4(0.f, 0.f, 0.f, 0.f);
        if (r + lr < n)
            xv = *(const float4*)(Xc + (size_t)(r + lr) * 64 + lc * 4);
        float xr[4] = {xv.x, xv.y, xv.z, xv.w};

        float a0 = 0.f, a1 = 0.f, a2 = 0.f, a3 = 0.f;
        #pragma unroll
        for (int k = 0; k < 64; ++k) {
            float w = Wreg[k];
            a0 = fmaf(bcastf(xr[k & 3],      (k >> 2)), w, a0);
            a1 = fmaf(bcastf(xr[k & 3], 16 + (k >> 2)), w, a1);
            a2 = fmaf(bcastf(xr[k & 3], 32 + (k >> 2)), w, a2);
            a3 = fmaf(bcastf(xr[k & 3], 48 + (k >> 2)), w, a3);
        }
        if (r + 0 < n) xws[(size_t)(r + 0) * 64 + lane] = f2bf(a0 * dinv[r + 0]);
        if (r + 1 < n) xws[(size_t)(r + 1) * 64 + lane] = f2bf(a1 * dinv[r + 1]);
        if (r + 2 < n) xws[(size_t)(r + 2) * 64 + lane] = f2bf(a2 * dinv[r + 2]);
        if (r + 3 < n) xws[(size_t)(r + 3) * 64 + lane] = f2bf(a3 * dinv[r + 3]);
    }
}

// ---------------------------------------------------------------------------
// pull aggregation (pre-scaled xws, weight-free) + leakyReLU + residual +
// running sum. One wave per node, lane = channel. Slim VGPR for occupancy.
// ---------------------------------------------------------------------------
__global__ __launch_bounds__(256) void agg_kernel(
        const ushort_t* __restrict__ xws,
        const int* __restrict__ rowptr,
        const int* __restrict__ csr,
        const float* __restrict__ dinv,
        const float* __restrict__ b,
        const float* __restrict__ xin,
        float* __restrict__ xout,
        const float* __restrict__ rin,
        float* __restrict__ rout,
        float scale, int n) {
    int tid = threadIdx.x;
    int c   = tid & 63;
    int wid = blockIdx.x * 4 + (tid >> 6);
    if (wid >= n) return;

    float dv  = dinv[wid];
    size_t vo = (size_t)wid * 64 + c;
    float acc = bf2f(xws[vo]);               // self term (already * dv)

    int beg = rowptr[wid];
    int end = rowptr[wid + 1];
    for (int base = beg; base < end; base += 64) {
        int m = end - base; if (m > 64) m = 64;   // multiple of 8
        int ce = csr[base + c];                   // coalesced segment load
        int j0 = 0;
        for (; j0 + 16 <= m; j0 += 16) {
            float g[16];
            #pragma unroll
            for (int j = 0; j < 16; ++j) {
                int s = __builtin_amdgcn_readlane(ce, j0 + j);
                g[j] = bf2f(xws[(size_t)(unsigned)s * 64 + c]);
            }
            #pragma unroll
            for (int j = 0; j < 16; ++j) acc += g[j];
        }
        if (j0 < m) {                             // exactly 8 left
            float g[8];
            #pragma unroll
            for (int j = 0; j < 8; ++j) {
                int s = __builtin_amdgcn_readlane(ce, j0 + j);
                g[j] = bf2f(xws[(size_t)(unsigned)s * 64 + c]);
            }
            #pragma unroll
            for (int j = 0; j < 8; ++j) acc += g[j];
        }
    }

    float r0  = b[c] + dv * acc;
    float act = r0 >= 0.f ? r0 : NEG_SLOPE * r0;
    float xn  = act + xin[vo];
    xout[vo] = xn;
    rout[vo] = rin[vo] + xn * scale;
}

extern "C" void kernel_launch(void* const* d_in, const int* in_sizes, int n_in,
                              void* d_out, int out_size, void* d_ws, size_t ws_size,
                              hipStream_t stream) {
    const float* X   = (const float*)d_in[0];
    const int*   adj = (const int*)d_in[1];
    const float* W   = (const float*)d_in[2];
    const float* b   = (const float*)d_in[3];
    float* out = (float*)d_out;

    const int nd = in_sizes[0];          // N * 64
    const int n  = nd >> 6;              // N
    const int e  = in_sizes[1] / 2;      // E
    const int L  = in_sizes[3] / 64;     // layers (3)

    const int* src = adj;
    const int* dst = adj + e;

    const int B  = 256;
    const int nb = (n + B - 1) / B;
    const int nb_buckets = (n + (1 << BSHIFT) - 1) >> BSHIFT;   // <= 256
    const int nch = (e + CHUNK - 1) / CHUNK;
    const int M   = nb_buckets * nch;                           // <= 8192
    const int csr_len = e + 8 * n + 64;

    // workspace layout (8B-aligned first)
    int2*  ebuf   = (int2*)d_ws;                        // e int2
    int*   csr    = (int*)(ebuf + e);                   // csr_len
    int*   m      = csr + csr_len;                      // 8192
    int*   cnt    = m + 8192;                           // n
    int*   bsum   = cnt + n;                            // nb
    int*   rowptr = bsum + nb;                          // n+1
    int*   cursor = rowptr + (n + 1);                   // n
    float* dinv   = (float*)(cursor + n);               // n
    float* Xcur   = dinv + n;                           // nd f32
    ushort_t* xwsA = (ushort_t*)(Xcur + (size_t)nd);    // nd + 64 bf16
    ushort_t* xwsB = xwsA + (size_t)nd + 64;            // nd + 64 bf16

    // ---- preprocessing: degrees + bucketed CSR build ----
    hipMemsetAsync(cnt, 0, (size_t)n * sizeof(int), stream);
    hist_kernel<<<nch, 1024, 0, stream>>>(dst, cnt, m, e, nb_buckets, nch);
    blocksum_kernel<<<nb, B, 0, stream>>>(cnt, bsum, n);
    scanb_kernel<<<1, 1024, 0, stream>>>(bsum, nb);
    rowptr_kernel<<<nb, B, 0, stream>>>(cnt, bsum, rowptr, cursor, dinv,
                                        csr, csr_len, xwsA, xwsB, n);
    scanm_kernel<<<1, 1024, 0, stream>>>(m, M);
    reorder_kernel<<<nch, 1024, 0, stream>>>(src, dst, m, ebuf, e, nb_buckets, nch);
    localfill_kernel<<<nb_buckets, 1024, 0, stream>>>(ebuf, m, cursor, csr,
                                                      e, nb_buckets, nch);

    // ---- layers ----
    int gemm_blocks = (n + 63) / 64;
    int agg_blocks  = (n + 3) / 4;
    ushort_t* xws_cur = xwsA;
    ushort_t* xws_nxt = xwsB;
    for (int i = 0; i < L; ++i) {
        const float* Wi  = W + (size_t)i * 64 * 64;
        const float* bi  = b + (size_t)i * 64;
        const float* xin = (i == 0) ? X : Xcur;
        const float* rin = (i == 0) ? X : out;
        gemm_rl<<<gemm_blocks, B, 0, stream>>>(xin, Wi, dinv, xws_cur, n);
        agg_kernel<<<agg_blocks, B, 0, stream>>>(xws_cur, rowptr, csr, dinv, bi,
                                                 xin, Xcur, rin, out,
                                                 1.0f / (float)(i + 2), n);
        ushort_t* t = xws_cur; xws_cur = xws_nxt; xws_nxt = t;
    }
}

// Round 7
// 372.486 us; speedup vs baseline: 1.2302x; 1.2302x over previous
//
#include <hip/hip_runtime.h>

#define NEG_SLOPE 0.01f
typedef unsigned short ushort_t;

#define CHUNK 32768       // edges per histogram/reorder block
#define BSHIFT 9          // 512 nodes per dst-bucket (nb_buckets <= 256)

static __device__ __forceinline__ float bf2f(ushort_t u) {
    return __uint_as_float(((unsigned int)u) << 16);
}
static __device__ __forceinline__ ushort_t f2bf(float f) {
    unsigned int x = __float_as_uint(f);
    x += 0x7fffu + ((x >> 16) & 1u);   // round-to-nearest-even
    return (ushort_t)(x >> 16);
}
static __device__ __forceinline__ float bcastf(float v, int lane) {
    return __int_as_float(__builtin_amdgcn_readlane(__float_as_int(v), lane));
}

// ---------------------------------------------------------------------------
// phase A: per-chunk dst-bucket histogram — LDS only, no global atomics
// ---------------------------------------------------------------------------
__global__ __launch_bounds__(1024) void hist_kernel(const int* __restrict__ dst,
                                                    int* __restrict__ m,
                                                    int e, int nbk, int nch) {
    __shared__ int lcnt[256];
    int t = threadIdx.x;
    if (t < 256) lcnt[t] = 0;
    __syncthreads();
    int base = blockIdx.x * CHUNK;
    int lim  = e - base; if (lim > CHUNK) lim = CHUNK;
    for (int j = t; j < lim; j += 1024)
        atomicAdd(&lcnt[dst[base + j] >> BSHIFT], 1);
    __syncthreads();
    if (t < nbk) m[t * nch + blockIdx.x] = lcnt[t];   // bucket-major
}

// exclusive scan of m[0..M) in place (single block, 8/thread, M<=8192)
__global__ __launch_bounds__(1024) void scanm_kernel(int* __restrict__ m, int M) {
    __shared__ int ts[1024];
    int t = threadIdx.x;
    int v[8], p[8];
    int s = 0;
    #pragma unroll
    for (int j = 0; j < 8; ++j) {
        int idx = t * 8 + j;
        v[j] = (idx < M) ? m[idx] : 0;
        s += v[j];
        p[j] = s;
    }
    ts[t] = s;
    __syncthreads();
    for (int st = 1; st < 1024; st <<= 1) {
        int x = (t >= st) ? ts[t - st] : 0;
        __syncthreads();
        ts[t] += x;
        __syncthreads();
    }
    int texcl = (t == 0) ? 0 : ts[t - 1];
    #pragma unroll
    for (int j = 0; j < 8; ++j) {
        int idx = t * 8 + j;
        if (idx < M) m[idx] = texcl + p[j] - v[j];
    }
}

// phase B: reorder edges into bucket-grouped ebuf (contiguous runs per chunk)
__global__ __launch_bounds__(1024) void reorder_kernel(const int* __restrict__ src,
                                                       const int* __restrict__ dst,
                                                       const int* __restrict__ m,
                                                       int2* __restrict__ ebuf,
                                                       int e, int nbk, int nch) {
    __shared__ int cur[256];
    int t = threadIdx.x;
    if (t < nbk) cur[t] = m[t * nch + blockIdx.x];
    __syncthreads();
    int base = blockIdx.x * CHUNK;
    int lim  = e - base; if (lim > CHUNK) lim = CHUNK;
    for (int j = t; j < lim; j += 1024) {
        int i = base + j;
        int d = dst[i];
        int pos = atomicAdd(&cur[d >> BSHIFT], 1);
        ebuf[pos] = make_int2(src[i], d);
    }
}

// phase C: per-bucket degree count (LDS) -> dinv, padded degree, bucket total
__global__ __launch_bounds__(1024) void bucket_deg_kernel(const int2* __restrict__ ebuf,
                                                          const int* __restrict__ m,
                                                          float* __restrict__ dinv,
                                                          int* __restrict__ pdeg,
                                                          int* __restrict__ btot,
                                                          int e, int nbk, int nch, int n) {
    __shared__ int lc[512];
    int t = threadIdx.x;
    int b = blockIdx.x;
    if (t < 512) lc[t] = 0;
    __syncthreads();
    int bs = m[b * nch];
    int be = (b + 1 < nbk) ? m[(b + 1) * nch] : e;
    for (int i = bs + t; i < be; i += 1024)
        atomicAdd(&lc[ebuf[i].y & 511], 1);
    __syncthreads();
    int v  = (b << BSHIFT) + t;
    int pd = 0;
    if (t < 512 && v < n) {
        int deg = lc[t];
        dinv[v] = rsqrtf((float)deg + 1.0f);
        pd = (deg + 7) & ~7;
        pdeg[v] = pd;
    }
    __syncthreads();
    if (t < 512) lc[t] = pd;
    __syncthreads();
    for (int s = 256; s > 0; s >>= 1) {
        if (t < s) lc[t] += lc[t + s];
        __syncthreads();
    }
    if (t == 0) btot[b] = lc[0];
}

// exclusive scan of btot[196]; rowptr[n]; zero sentinel xws rows
__global__ __launch_bounds__(256) void scanb2_kernel(int* __restrict__ btot,
                                                     int* __restrict__ rowptr,
                                                     ushort_t* __restrict__ xwsA,
                                                     ushort_t* __restrict__ xwsB,
                                                     int nbk, int n) {
    __shared__ int l[256];
    int t = threadIdx.x;
    l[t] = (t < nbk) ? btot[t] : 0;
    __syncthreads();
    for (int s = 1; s < 256; s <<= 1) {
        int v = (t >= s) ? l[t - s] : 0;
        __syncthreads();
        l[t] += v;
        __syncthreads();
    }
    if (t < nbk) btot[t] = (t == 0) ? 0 : l[t - 1];
    if (t == 0)  rowptr[n] = l[255];
    if (t < 64) {
        xwsA[(size_t)n * 64 + t] = 0;
        xwsB[(size_t)n * 64 + t] = 0;
    }
}

// phase D: per-bucket rowptr (LDS scan) + CSR fill with LDS cursors
// all csr writes land in this bucket's contiguous ~32KB slice (L2-local)
__global__ __launch_bounds__(1024) void localfill_kernel(const int2* __restrict__ ebuf,
                                                         const int* __restrict__ m,
                                                         const int* __restrict__ pdeg,
                                                         const int* __restrict__ btot,
                                                         int* __restrict__ rowptr,
                                                         int* __restrict__ csr,
                                                         int e, int nbk, int nch, int n) {
    __shared__ int pref[512];
    __shared__ int cur[512];
    int t = threadIdx.x;
    int b = blockIdx.x;
    int v = (b << BSHIFT) + t;
    int pd = (t < 512 && v < n) ? pdeg[v] : 0;
    if (t < 512) pref[t] = pd;
    __syncthreads();
    for (int s = 1; s < 512; s <<= 1) {
        int x = (t < 512 && t >= s) ? pref[t - s] : 0;
        __syncthreads();
        if (t < 512) pref[t] += x;
        __syncthreads();
    }
    int base = btot[b];
    int mybase = 0;
    if (t < 512) {
        mybase = base + pref[t] - pd;   // exclusive
        if (v < n) rowptr[v] = mybase;
        cur[t] = mybase;
    }
    __syncthreads();
    int bs = m[b * nch];
    int be = (b + 1 < nbk) ? m[(b + 1) * nch] : e;
    for (int i = bs + t; i < be; i += 1024) {
        int2 ed = ebuf[i];
        int slot = atomicAdd(&cur[ed.y & 511], 1);
        csr[slot] = ed.x;
    }
    __syncthreads();
    if (t < 512 && v < n) {
        int endp = mybase + pd;
        for (int s2 = cur[t]; s2 < endp; ++s2) csr[s2] = n;   // pad sentinels
    }
}

// ---------------------------------------------------------------------------
// xws = (Xc @ W) * dinv[row]  (f32 in, bf16 out). W column in lane VGPRs.
// ---------------------------------------------------------------------------
__global__ __launch_bounds__(256) void gemm_rl(const float* __restrict__ Xc,
                                               const float* __restrict__ W,
                                               const float* __restrict__ dinv,
                                               ushort_t* __restrict__ xws, int n) {
    int lane = threadIdx.x & 63;
    int wv   = threadIdx.x >> 6;

    float Wreg[64];
    #pragma unroll
    for (int k = 0; k < 64; ++k) Wreg[k] = W[k * 64 + lane];

    int row0 = blockIdx.x * 64 + wv * 16;
    int lr = lane >> 4;
    int lc = lane & 15;

    #pragma unroll 1
    for (int it = 0; it < 4; ++it) {
        int r = row0 + it * 4;
        float4 xv = make_float4(0.f, 0.f, 0.f, 0.f);
        if (r + lr < n)
            xv = *(const float4*)(Xc + (size_t)(r + lr) * 64 + lc * 4);
        float xr[4] = {xv.x, xv.y, xv.z, xv.w};

        float a0 = 0.f, a1 = 0.f, a2 = 0.f, a3 = 0.f;
        #pragma unroll
        for (int k = 0; k < 64; ++k) {
            float w = Wreg[k];
            a0 = fmaf(bcastf(xr[k & 3],      (k >> 2)), w, a0);
            a1 = fmaf(bcastf(xr[k & 3], 16 + (k >> 2)), w, a1);
            a2 = fmaf(bcastf(xr[k & 3], 32 + (k >> 2)), w, a2);
            a3 = fmaf(bcastf(xr[k & 3], 48 + (k >> 2)), w, a3);
        }
        if (r + 0 < n) xws[(size_t)(r + 0) * 64 + lane] = f2bf(a0 * dinv[r + 0]);
        if (r + 1 < n) xws[(size_t)(r + 1) * 64 + lane] = f2bf(a1 * dinv[r + 1]);
        if (r + 2 < n) xws[(size_t)(r + 2) * 64 + lane] = f2bf(a2 * dinv[r + 2]);
        if (r + 3 < n) xws[(size_t)(r + 3) * 64 + lane] = f2bf(a3 * dinv[r + 3]);
    }
}

// ---------------------------------------------------------------------------
// pull aggregation: TWO nodes per wave, interleaved 8+8 gather groups
// (sustains ~16-32 outstanding gathers; halves per-node pro/epilogue cost)
// ---------------------------------------------------------------------------
__global__ __launch_bounds__(256) void agg_kernel(
        const ushort_t* __restrict__ xws,
        const int* __restrict__ rowptr,
        const int* __restrict__ csr,
        const float* __restrict__ dinv,
        const float* __restrict__ bias,
        const float* __restrict__ xin,
        float* __restrict__ xout,
        const float* __restrict__ rin,
        float* __restrict__ rout,
        float scale, int n) {
    int tid = threadIdx.x;
    int c   = tid & 63;
    int w   = blockIdx.x * 4 + (tid >> 6);
    int v0  = w * 2;
    if (v0 >= n) return;
    int  v1   = v0 + 1;
    bool has1 = (v1 < n);
    int  v1c  = has1 ? v1 : v0;

    int rp0 = rowptr[v0];
    int rp1 = rowptr[v0 + 1];
    int rp2 = rowptr[v1c + 1];
    int b0 = rp0,                len0 = rp1 - rp0;
    int b1 = has1 ? rp1 : rp0;   int len1 = rp2 - b1;

    size_t vo0 = (size_t)v0  * 64 + c;
    size_t vo1 = (size_t)v1c * 64 + c;
    float acc0 = bf2f(xws[vo0]);     // self term (pre-scaled by dinv)
    float acc1 = bf2f(xws[vo1]);

    for (int off = 0; ; off += 64) {
        int r0 = len0 - off;
        int r1 = len1 - off;
        if (r0 <= 0 && r1 <= 0) break;
        int ce0 = (c < r0) ? csr[b0 + off + c] : n;
        int ce1 = (c < r1) ? csr[b1 + off + c] : n;
        int m0 = r0 < 64 ? r0 : 64;
        int m1 = r1 < 64 ? r1 : 64;
        int mx = m0 > m1 ? m0 : m1;
        for (int j0 = 0; j0 < mx; j0 += 8) {
            float g0[8], g1[8];
            bool p0 = j0 < m0, p1 = j0 < m1;
            if (p0) {
                #pragma unroll
                for (int j = 0; j < 8; ++j) {
                    int s = __builtin_amdgcn_readlane(ce0, j0 + j);
                    g0[j] = bf2f(xws[(size_t)(unsigned)s * 64 + c]);
                }
            }
            if (p1) {
                #pragma unroll
                for (int j = 0; j < 8; ++j) {
                    int s = __builtin_amdgcn_readlane(ce1, j0 + j);
                    g1[j] = bf2f(xws[(size_t)(unsigned)s * 64 + c]);
                }
            }
            if (p0) {
                #pragma unroll
                for (int j = 0; j < 8; ++j) acc0 += g0[j];
            }
            if (p1) {
                #pragma unroll
                for (int j = 0; j < 8; ++j) acc1 += g1[j];
            }
        }
        if (r0 <= 64 && r1 <= 64) break;
    }

    float dv0 = dinv[v0];
    float t0  = bias[c] + dv0 * acc0;
    float a0  = t0 >= 0.f ? t0 : NEG_SLOPE * t0;
    float xn0 = a0 + xin[vo0];
    xout[vo0] = xn0;
    rout[vo0] = rin[vo0] + xn0 * scale;
    if (has1) {
        float dv1 = dinv[v1];
        float t1  = bias[c] + dv1 * acc1;
        float a1  = t1 >= 0.f ? t1 : NEG_SLOPE * t1;
        float xn1 = a1 + xin[vo1];
        xout[vo1] = xn1;
        rout[vo1] = rin[vo1] + xn1 * scale;
    }
}

extern "C" void kernel_launch(void* const* d_in, const int* in_sizes, int n_in,
                              void* d_out, int out_size, void* d_ws, size_t ws_size,
                              hipStream_t stream) {
    const float* X   = (const float*)d_in[0];
    const int*   adj = (const int*)d_in[1];
    const float* W   = (const float*)d_in[2];
    const float* b   = (const float*)d_in[3];
    float* out = (float*)d_out;

    const int nd = in_sizes[0];          // N * 64
    const int n  = nd >> 6;              // N
    const int e  = in_sizes[1] / 2;      // E
    const int L  = in_sizes[3] / 64;     // layers (3)

    const int* src = adj;
    const int* dst = adj + e;

    const int nbk = (n + (1 << BSHIFT) - 1) >> BSHIFT;   // <= 256
    const int nch = (e + CHUNK - 1) / CHUNK;             // ~39
    const int M   = nbk * nch;                           // <= 8192
    const int csr_len = e + 8 * n + 64;

    // workspace layout (8B-aligned first)
    int2*  ebuf   = (int2*)d_ws;                        // e int2
    int*   csr    = (int*)(ebuf + e);                   // csr_len
    int*   m      = csr + csr_len;                      // 8192
    int*   pdeg   = m + 8192;                           // n
    int*   btot   = pdeg + n;                           // 256
    int*   rowptr = btot + 256;                         // n+1
    float* dinv   = (float*)(rowptr + n + 1);           // n
    float* Xcur   = dinv + n;                           // nd f32
    ushort_t* xwsA = (ushort_t*)(Xcur + (size_t)nd);    // nd + 64 bf16
    ushort_t* xwsB = xwsA + (size_t)nd + 64;            // nd + 64 bf16

    // ---- preprocessing: bucketed CSR build, no random global writes ----
    hist_kernel<<<nch, 1024, 0, stream>>>(dst, m, e, nbk, nch);
    scanm_kernel<<<1, 1024, 0, stream>>>(m, M);
    reorder_kernel<<<nch, 1024, 0, stream>>>(src, dst, m, ebuf, e, nbk, nch);
    bucket_deg_kernel<<<nbk, 1024, 0, stream>>>(ebuf, m, dinv, pdeg, btot,
                                                e, nbk, nch, n);
    scanb2_kernel<<<1, 256, 0, stream>>>(btot, rowptr, xwsA, xwsB, nbk, n);
    localfill_kernel<<<nbk, 1024, 0, stream>>>(ebuf, m, pdeg, btot, rowptr, csr,
                                               e, nbk, nch, n);

    // ---- layers ----
    int gemm_blocks = (n + 63) / 64;
    int agg_blocks  = (n + 7) / 8;       // 2 nodes per wave, 4 waves per block
    ushort_t* xws_cur = xwsA;
    ushort_t* xws_nxt = xwsB;
    for (int i = 0; i < L; ++i) {
        const float* Wi  = W + (size_t)i * 64 * 64;
        const float* bi  = b + (size_t)i * 64;
        const float* xin = (i == 0) ? X : Xcur;
        const float* rin = (i == 0) ? X : out;
        gemm_rl<<<gemm_blocks, 256, 0, stream>>>(xin, Wi, dinv, xws_cur, n);
        agg_kernel<<<agg_blocks, 256, 0, stream>>>(xws_cur, rowptr, csr, dinv, bi,
                                                   xin, Xcur, rin, out,
                                                   1.0f / (float)(i + 2), n);
        ushort_t* t = xws_cur; xws_cur = xws_nxt; xws_nxt = t;
    }
}